// Round 2
// baseline (278.382 us; speedup 1.0000x reference)
//
#include <hip/hip_runtime.h>

// CellListNL MIC neighbor predicate, N=4096, rc=5, cell = L*I (diagonal).
// Output layout (single fp32 buffer, concatenated flat in return order):
//   out[0 .. N*N)           : d2_masked[i][j]
//   out[N*N .. N*N + N*N*3) : shift[i][j][c] as float (-1/0/1), 0 if not kept
//
// Round 3: exploit sparsity. Output is ~99.2% zeros (expected kept pairs
// = N * (4pi/3) rc^3 / L^3 ~ 137K of 16.7M). Two very different fused
// store schedules (R0 narrow stores, R1 LDS-transposed dwordx4) both sat
// at ~3 TB/s effective, while the harness's fillBufferAligned hits
// 6.3 TB/s on this same buffer. So:
//   K1 zero_kernel : fill-clone, zeroes all 268 MB at fill rate (~43 us)
//   K2 pairs_kernel: evaluates all pairs, writes ONLY kept entries
//                    (scattered dword d2 + dwordx3 shift; mostly-empty
//                    exec masks, ~10 us). Stream order serializes K1->K2.

constexpr int   N_ATOMS = 4096;
constexpr float RC2     = 25.0f;   // rc = 5.0

typedef float v3f __attribute__((ext_vector_type(3)));  // -> global_store_dwordx3
typedef float v4f __attribute__((ext_vector_type(4)));  // -> global_store_dwordx4

// ---------------------------------------------------------------------------
// K1: zero the entire output buffer, mirroring __amd_rocclr_fillBufferAligned:
// contiguous dwordx4 per instruction, 16 stores/thread, 64 KB per block.
// 4096 blocks x 256 threads x 16 x 16 B = 268,435,456 B exactly.
__global__ __launch_bounds__(256) void zero_kernel(v4f* __restrict__ out)
{
    const int base = blockIdx.x * (256 * 16) + threadIdx.x;
    #pragma unroll
    for (int k = 0; k < 16; ++k) {
        out[base + k * 256] = (v4f){0.0f, 0.0f, 0.0f, 0.0f};
    }
}

// ---------------------------------------------------------------------------
// K2: one pair per thread (Round-0 structure, known-good math/mapping),
// but all stores predicated on keep / nonzero-shift.
__global__ __launch_bounds__(256) void pairs_kernel(
    const float* __restrict__ coord,
    const float* __restrict__ cell,
    float* __restrict__ out)
{
    const float L   = cell[0];          // cell = L * I
    const float inv = 1.0f / L;

    const int i = blockIdx.x >> 4;                       // block-uniform
    const int j = ((blockIdx.x & 15) << 8) + threadIdx.x;

    // frac_i: block-uniform -> scalar loads
    float fix = coord[3 * i + 0] * inv; fix -= floorf(fix);
    float fiy = coord[3 * i + 1] * inv; fiy -= floorf(fiy);
    float fiz = coord[3 * i + 2] * inv; fiz -= floorf(fiz);

    // frac_j: per-lane 12B load (dwordx3); coord = 48 KB -> L1/L2 resident
    const v3f cjv = *reinterpret_cast<const v3f*>(coord + 3 * j);
    float fjx = cjv.x * inv; fjx -= floorf(fjx);
    float fjy = cjv.y * inv; fjy -= floorf(fjy);
    float fjz = cjv.z * inv; fjz -= floorf(fjz);

    // dfrac = frac_j - frac_i; MIC shift = -round_half_even(dfrac)
    float dx = fjx - fix, dy = fjy - fiy, dz = fjz - fiz;
    const float sx = -rintf(dx), sy = -rintf(dy), sz = -rintf(dz);
    dx = (dx + sx) * L; dy = (dy + sy) * L; dz = (dz + sz) * L;

    const float dist2 = dx * dx + dy * dy + dz * dz;
    const bool  keep  = (dist2 > 0.0f) && (dist2 < RC2);

    if (keep) {
        const size_t p = (size_t)i * N_ATOMS + j;
        out[p] = dist2;                                  // scattered dword
        // shift nonzero only for boundary-crossing kept pairs (rarer still)
        if ((sx != 0.0f) | (sy != 0.0f) | (sz != 0.0f)) {
            v3f sv; sv.x = sx; sv.y = sy; sv.z = sz;
            *reinterpret_cast<v3f*>(
                out + (size_t)N_ATOMS * N_ATOMS + p * 3) = sv;  // dwordx3
        }
    }
}

// ---------------------------------------------------------------------------
extern "C" void kernel_launch(void* const* d_in, const int* in_sizes, int n_in,
                              void* d_out, int out_size, void* d_ws, size_t ws_size,
                              hipStream_t stream) {
    const float* coord = (const float*)d_in[0];   // [4096, 3] fp32
    const float* cell  = (const float*)d_in[1];   // [3, 3] fp32, L*I
    float* out = (float*)d_out;                    // 4096^2 + 4096^2*3 fp32

    // K1: zero 268 MB at fill rate (4096 blocks cover the buffer exactly)
    hipLaunchKernelGGL(zero_kernel, dim3(4096), dim3(256), 0, stream,
                       (v4f*)out);

    // K2: sparse writes of kept pairs only (stream-ordered after K1)
    hipLaunchKernelGGL(pairs_kernel, dim3(N_ATOMS * (N_ATOMS / 256)), dim3(256),
                       0, stream, coord, cell, out);
}

// Round 3
// 275.513 us; speedup vs baseline: 1.0104x; 1.0104x over previous
//
#include <hip/hip_runtime.h>

// CellListNL MIC neighbor predicate, N=4096, rc=5, cell = L*I (diagonal).
// Output layout (single fp32 buffer, concatenated flat in return order):
//   out[0 .. N*N)           : d2_masked[i][j]
//   out[N*N .. N*N + N*N*3) : shift[i][j][c] as float (-1/0/1), 0 if not kept
//
// Round 4: timing decomposes as ~161us harness poison fill (in the timed
// graph, untouchable) + our kernels. Output is ~99.2% zeros. R2 proved the
// sparse pairs kernel is ~12us, but my hand-rolled zero clone ran at
// ~2.5 TB/s while rocclr's fillBufferAligned does the same job at 6.6 TB/s.
// So: stop hand-rolling the fill. hipMemsetAsync is stream-ordered and
// graph-capturable (memset node -> the same fillBufferAligned we profiled);
// let it write the 268 MB of zeros, then the sparse kernel writes only the
// ~137K kept pairs (scattered dword d2 + dwordx3 shift).

constexpr int   N_ATOMS = 4096;
constexpr float RC2     = 25.0f;   // rc = 5.0

typedef float v3f __attribute__((ext_vector_type(3)));  // -> global_store_dwordx3

// ---------------------------------------------------------------------------
// One pair per thread (R0/R2 structure, harness-verified mapping), all
// stores predicated on keep / nonzero-shift.
__global__ __launch_bounds__(256) void pairs_kernel(
    const float* __restrict__ coord,
    const float* __restrict__ cell,
    float* __restrict__ out)
{
    const float L   = cell[0];          // cell = L * I
    const float inv = 1.0f / L;

    const int i = blockIdx.x >> 4;                       // block-uniform
    const int j = ((blockIdx.x & 15) << 8) + threadIdx.x;

    // frac_i: block-uniform -> scalar loads
    float fix = coord[3 * i + 0] * inv; fix -= floorf(fix);
    float fiy = coord[3 * i + 1] * inv; fiy -= floorf(fiy);
    float fiz = coord[3 * i + 2] * inv; fiz -= floorf(fiz);

    // frac_j: per-lane 12B load (dwordx3); coord = 48 KB -> L1/L2 resident
    const v3f cjv = *reinterpret_cast<const v3f*>(coord + 3 * j);
    float fjx = cjv.x * inv; fjx -= floorf(fjx);
    float fjy = cjv.y * inv; fjy -= floorf(fjy);
    float fjz = cjv.z * inv; fjz -= floorf(fjz);

    // dfrac = frac_j - frac_i; MIC shift = -round_half_even(dfrac)
    float dx = fjx - fix, dy = fjy - fiy, dz = fjz - fiz;
    const float sx = -rintf(dx), sy = -rintf(dy), sz = -rintf(dz);
    dx = (dx + sx) * L; dy = (dy + sy) * L; dz = (dz + sz) * L;

    const float dist2 = dx * dx + dy * dy + dz * dz;
    const bool  keep  = (dist2 > 0.0f) && (dist2 < RC2);

    if (keep) {
        const size_t p = (size_t)i * N_ATOMS + j;
        out[p] = dist2;                                  // scattered dword
        // shift nonzero only for boundary-crossing kept pairs (rarer still)
        if ((sx != 0.0f) | (sy != 0.0f) | (sz != 0.0f)) {
            v3f sv; sv.x = sx; sv.y = sy; sv.z = sz;
            *reinterpret_cast<v3f*>(
                out + (size_t)N_ATOMS * N_ATOMS + p * 3) = sv;  // dwordx3
        }
    }
}

// ---------------------------------------------------------------------------
extern "C" void kernel_launch(void* const* d_in, const int* in_sizes, int n_in,
                              void* d_out, int out_size, void* d_ws, size_t ws_size,
                              hipStream_t stream) {
    const float* coord = (const float*)d_in[0];   // [4096, 3] fp32
    const float* cell  = (const float*)d_in[1];   // [3, 3] fp32, L*I
    float* out = (float*)d_out;                    // 4096^2 + 4096^2*3 fp32

    // Zero all 268 MB via rocclr's fillBufferAligned (6.6 TB/s demonstrated),
    // graph-capturable as a memset node, stream-ordered before pairs_kernel.
    hipMemsetAsync(out, 0,
                   (size_t)N_ATOMS * N_ATOMS * 4 * sizeof(float), stream);

    // Sparse writes of kept pairs only.
    hipLaunchKernelGGL(pairs_kernel, dim3(N_ATOMS * (N_ATOMS / 256)), dim3(256),
                       0, stream, coord, cell, out);
}

// Round 4
// 261.489 us; speedup vs baseline: 1.0646x; 1.0536x over previous
//
#include <hip/hip_runtime.h>

// CellListNL MIC neighbor predicate, N=4096, rc=5, cell = L*I (diagonal).
// Output layout (single fp32 buffer, concatenated flat in return order):
//   out[0 .. N*N)           : d2_masked[i][j]
//   out[N*N .. N*N + N*N*3) : shift[i][j][c] as float (-1/0/1), 0 if not kept
//
// Round 5: clean NT-store isolation on the best kernel (R0, 94.6us portion).
// Evidence so far: in OUR timed window, every write mechanism (narrow stores,
// LDS-staged dwordx4, rocclr fillBufferAligned via memset) caps at
// ~2.6-2.85 TB/s, while the SAME rocclr fill hits 6.6 TB/s on the preceding
// poison pass. Limiter = cache state (write-allocate + dirty-poison L3
// eviction), not store pattern. The one untested lever: nontemporal stores
// (evict-first / no-allocate), isolated here with ZERO other changes vs R0 —
// no barriers, so the NT store queue is never force-drained mid-kernel.
//   d2   : dword nt store, lanes stride 4  -> 256 B/wave contiguous
//   shift: dwordx3 nt store, lanes stride 12 -> 768 B/wave contiguous

constexpr int N_ATOMS = 4096;
constexpr float RC2 = 25.0f;   // rc = 5.0

typedef float v3f __attribute__((ext_vector_type(3)));  // 12B -> global_store_dwordx3

__global__ __launch_bounds__(256) void cellnl_kernel(
    const float* __restrict__ coord,
    const float* __restrict__ cell,
    float* __restrict__ out)
{
    const float L   = cell[0];          // cell = L * I; inv(cell) = diag(1/L)
    const float inv = 1.0f / L;

    // i is BLOCK-uniform: 4096 j's per i, 256 threads/block, 16 blocks per row.
    const int i = blockIdx.x >> 4;
    const int j = ((blockIdx.x & 15) << 8) + threadIdx.x;

    // frac_i: block-uniform -> scalar loads
    float fix = coord[3 * i + 0] * inv; fix -= floorf(fix);
    float fiy = coord[3 * i + 1] * inv; fiy -= floorf(fiy);
    float fiz = coord[3 * i + 2] * inv; fiz -= floorf(fiz);

    // frac_j: per-lane 12B load (dwordx3), stride 12 -> L1-resident (coord = 48 KB)
    const v3f cjv = *reinterpret_cast<const v3f*>(coord + 3 * j);
    float fjx = cjv.x * inv; fjx -= floorf(fjx);
    float fjy = cjv.y * inv; fjy -= floorf(fjy);
    float fjz = cjv.z * inv; fjz -= floorf(fjz);

    // dfrac = frac_j - frac_i; MIC shift = -round_half_even(dfrac)
    float dx = fjx - fix, dy = fjy - fiy, dz = fjz - fiz;
    const float sx = -rintf(dx), sy = -rintf(dy), sz = -rintf(dz);  // v_rndne
    dx += sx; dy += sy; dz += sz;
    dx *= L; dy *= L; dz *= L;                 // dfrac @ cell (diagonal)

    const float dist2 = dx * dx + dy * dy + dz * dz;
    const bool keep = (dist2 > 0.0f) && (dist2 < RC2);

    const size_t p = (size_t)i * N_ATOMS + j;

    // d2: 4B/lane, wave = 256B contiguous, nontemporal (no L3 allocate)
    __builtin_nontemporal_store(keep ? dist2 : 0.0f, out + p);

    // shift: 12B/lane via dwordx3, wave = 768B contiguous, nontemporal
    v3f sv;
    sv.x = keep ? sx : 0.0f;
    sv.y = keep ? sy : 0.0f;
    sv.z = keep ? sz : 0.0f;
    __builtin_nontemporal_store(
        sv, reinterpret_cast<v3f*>(out + (size_t)N_ATOMS * N_ATOMS + p * 3));
}

extern "C" void kernel_launch(void* const* d_in, const int* in_sizes, int n_in,
                              void* d_out, int out_size, void* d_ws, size_t ws_size,
                              hipStream_t stream) {
    const float* coord = (const float*)d_in[0];   // [4096, 3] fp32
    const float* cell  = (const float*)d_in[1];   // [3, 3] fp32, L*I
    float* out = (float*)d_out;                    // 4096^2 + 4096^2*3 fp32

    const int blocks = N_ATOMS * (N_ATOMS / 256);  // one pair per thread
    hipLaunchKernelGGL(cellnl_kernel, dim3(blocks), dim3(256), 0, stream,
                       coord, cell, out);
}